// Round 13
// baseline (488.022 us; speedup 1.0000x reference)
//
#include <hip/hip_runtime.h>
#include <hip/hip_fp16.h>

#define NN     65536    // total nodes
#define EE     2097152  // edges
#define HID    32
#define KCH    5
#define OUTS   33
#define NG     8
#define GSZ    262144   // INPUT_SIZE * HIDDEN per graph
#define WLP    40       // padded fp16 row length for Wl (80 B, 16B-aligned)
#define SLICES 64       // edge slices for src histogram
#define RSIZE  32768    // counters per range (2 ranges cover 64K nodes)
#define BSL    16384    // edges per bucketing slice (128 slices)
#define NBK    256      // coarse buckets (dst >> 8)
#define STG    9472     // LDS staging capacity in k_place

typedef _Float16 half8 __attribute__((ext_vector_type(8)));
typedef float floatx4 __attribute__((ext_vector_type(4)));
typedef unsigned uintx4 __attribute__((ext_vector_type(4)));   // native vec for nt loads

// exclusive scan of sh[0..255] in place; whole block must call
__device__ __forceinline__ void exscan256(int tid, int* __restrict__ sh,
                                          int* __restrict__ wsc) {
    int v = 0, s = 0;
    if (tid < 256) {
        v = sh[tid];
        s = v;
        int lane = tid & 63;
        #pragma unroll
        for (int off = 1; off < 64; off <<= 1) {
            int t = __shfl_up(s, off, 64);
            if (lane >= off) s += t;
        }
        if (lane == 63) wsc[tid >> 6] = s;
    }
    __syncthreads();
    if (tid == 0) {
        int a = 0;
        #pragma unroll
        for (int i = 0; i < 4; ++i) { int t = wsc[i]; wsc[i] = a; a += t; }
    }
    __syncthreads();
    if (tid < 256) sh[tid] = s - v + wsc[tid >> 6];
    __syncthreads();
}

// ------- fused: src out-degree histogram (blocks 0..127) + dst bucket counts
__global__ __launch_bounds__(1024) void k_hist2(const int* __restrict__ ei,
                                                unsigned char* __restrict__ pdeg,
                                                int* __restrict__ bcnt) {
    __shared__ unsigned cnt[RSIZE];
    int b = blockIdx.x, tid = threadIdx.x;
    if (b < 128) {
        int r = (b >> 6) & 1, s = b & 63;
        const int* keys = ei + s * (EE / SLICES);
        unsigned char* pout = pdeg + (size_t)(r * SLICES + s) * RSIZE;
        for (int i = tid; i < RSIZE; i += 1024) cnt[i] = 0;
        __syncthreads();
        int lo = r * RSIZE, hi = lo + RSIZE;
        for (int i = tid; i < EE / SLICES; i += 1024) {
            int k = keys[i];
            if (k >= lo && k < hi) atomicAdd(&cnt[k - lo], 1u);
        }
        __syncthreads();
        unsigned* pout4 = (unsigned*)pout;
        for (int i = tid; i < RSIZE / 4; i += 1024) {
            unsigned c0 = cnt[4 * i], c1 = cnt[4 * i + 1];
            unsigned c2 = cnt[4 * i + 2], c3 = cnt[4 * i + 3];
            pout4[i] = c0 | (c1 << 8) | (c2 << 16) | (c3 << 24);
        }
    } else {
        int s = b - 128;
        if (tid < NBK) cnt[tid] = 0;
        __syncthreads();
        const int* dsts = ei + EE + s * BSL;
        for (int i = tid; i < BSL; i += 1024)
            atomicAdd(&cnt[dsts[i] >> 8], 1u);
        __syncthreads();
        if (tid < NBK) bcnt[s * NBK + tid] = (int)cnt[tid];
    }
}

// ------- fused: partial-hist reduce -> dinv (blocks 0..63) + bucket scan ----
__global__ __launch_bounds__(256) void k_hredscan(const unsigned char* __restrict__ pdeg,
                                                  float* __restrict__ dinv,
                                                  int* __restrict__ bcnt,
                                                  int* __restrict__ bbase) {
    int blk = blockIdx.x, tid = threadIdx.x;
    if (blk < 64) {
        int t = blk * 256 + tid;
        int r = t >> 13, ql = t & 8191;
        const unsigned* base = (const unsigned*)(pdeg + (size_t)r * SLICES * RSIZE) + ql;
        unsigned s0 = 0, s1 = 0, s2 = 0, s3 = 0;
#pragma unroll 8
        for (int s = 0; s < SLICES; ++s) {
            unsigned v = base[s * (RSIZE / 4)];
            s0 += v & 0xFF; s1 += (v >> 8) & 0xFF; s2 += (v >> 16) & 0xFF; s3 += v >> 24;
        }
        int c = (r << 15) + 4 * ql;
        dinv[c]     = s0 ? 1.0f / sqrtf((float)s0) : 0.0f;
        dinv[c + 1] = s1 ? 1.0f / sqrtf((float)s1) : 0.0f;
        dinv[c + 2] = s2 ? 1.0f / sqrtf((float)s2) : 0.0f;
        dinv[c + 3] = s3 ? 1.0f / sqrtf((float)s3) : 0.0f;
    } else {
        __shared__ int tot[256];
        __shared__ int wsc[4];
        int b = tid;
        int run = 0;
        for (int s = 0; s < 128; ++s) {
            int c = bcnt[s * NBK + b];
            bcnt[s * NBK + b] = run;
            run += c;
        }
        tot[b] = run;
        __syncthreads();
        exscan256(b, tot, wsc);
        bbase[b] = tot[b];
        if (b == 0) bbase[256] = EE;
        for (int s = 0; s < 128; ++s)
            bcnt[s * NBK + b] += tot[b];
    }
}

// ---------------- coarse bucketing: LDS counting sort, coalesced flush ------
__global__ __launch_bounds__(1024) void k_bucket(const int* __restrict__ ei,
                                                 const int* __restrict__ boff,
                                                 unsigned* __restrict__ bkt) {
    __shared__ unsigned stage[BSL];
    __shared__ int cnt[NBK], cur[NBK], gbase[NBK];
    __shared__ int wsc[4];
    int s = blockIdx.x, tid = threadIdx.x;
    if (tid < NBK) cnt[tid] = 0;
    __syncthreads();
    const int* srcs = ei + s * BSL;
    const int* dsts = ei + EE + s * BSL;
    for (int i = tid; i < BSL; i += 1024)
        atomicAdd(&cnt[dsts[i] >> 8], 1);
    __syncthreads();
    if (tid < NBK) gbase[tid] = boff[s * NBK + tid];
    exscan256(tid, cnt, wsc);
    if (tid < NBK) cur[tid] = cnt[tid];
    __syncthreads();
    for (int i = tid; i < BSL; i += 1024) {
        int d = dsts[i];
        int pos = atomicAdd(&cur[d >> 8], 1);
        stage[pos] = (unsigned)srcs[i] | ((unsigned)d << 16);
    }
    __syncthreads();
    for (int j = tid; j < BSL; j += 1024) {
        unsigned rec = stage[j];
        int b = rec >> 24;
        bkt[gbase[b] + (j - cnt[b])] = rec;
    }
}

// ---------------- fine placement: exact CSR, packed ep, rowp ----------------
__global__ __launch_bounds__(512) void k_place(const unsigned* __restrict__ bkt,
                                               const int* __restrict__ bbase,
                                               const float* __restrict__ dinv,
                                               unsigned* __restrict__ ep,
                                               int* __restrict__ rowp) {
    __shared__ unsigned stage[STG];
    __shared__ int hist[NBK], cur[NBK];
    __shared__ float dl[NBK];
    __shared__ int wsc[4];
    int b = blockIdx.x, tid = threadIdx.x;
    int base = bbase[b], cnt = bbase[b + 1] - base;
    if (tid < NBK) { hist[tid] = 0; dl[tid] = dinv[b * NBK + tid]; }
    __syncthreads();
    const unsigned* recs = bkt + base;
    for (int i = tid; i < cnt; i += 512)
        atomicAdd(&hist[(recs[i] >> 16) & 255], 1);
    __syncthreads();
    exscan256(tid, hist, wsc);
    if (tid < NBK) {
        cur[tid] = hist[tid];
        rowp[b * NBK + tid] = base + hist[tid];
    }
    if (b == 0 && tid == 0) rowp[NN] = EE;
    __syncthreads();
    for (int i = tid; i < cnt; i += 512) {
        unsigned rec = recs[i];
        int srcv = rec & 0xFFFF;
        int dlow = (rec >> 16) & 255;
        float nr = -(dinv[srcv] * dl[dlow]);
        unsigned pk = (unsigned)srcv |
                      ((unsigned)__half_as_ushort(__float2half(nr)) << 16);
        int pos = atomicAdd(&cur[dlow], 1);
        if (pos < STG) stage[pos] = pk; else ep[base + pos] = pk;
    }
    __syncthreads();
    int lim = cnt < STG ? cnt : STG;
    for (int j = tid; j < lim; j += 512)
        ep[base + j] = stage[j];
}

// ------- width-1 propagation: 4 lanes/node; nt loads for the ep stream ------
__global__ __launch_bounds__(256) void k_prop1(const int* __restrict__ rowp,
                                               const unsigned* __restrict__ ep,
                                               const float* __restrict__ tin,
                                               const float* __restrict__ prev,
                                               float* __restrict__ tout,
                                               float alpha) {
    int idx = blockIdx.x * 256 + threadIdx.x;
    int n = idx >> 2, l = idx & 3;
    int e0 = rowp[n], e1 = rowp[n + 1];
    float a = 0.f;
    for (int e = e0 + l; e < e1; e += 4) {
        unsigned p = __builtin_nontemporal_load(ep + e);
        a += __half2float(__ushort_as_half((unsigned short)(p >> 16))) * tin[p & 0xFFFF];
    }
    a += __shfl_xor(a, 1, 64);
    a += __shfl_xor(a, 2, 64);
    if (l == 0) {
        float r = alpha * a;
        if (prev) r -= prev[n];
        tout[n] = r;
    }
}

// ---- width-32 fp16 propagation: 4 lanes/node, 16B gathers, 8-edge unroll,
//      nontemporal ep loads (keep 4MB tin table L2-resident) -----------------
__global__ __launch_bounds__(256) void k_prop32(const int* __restrict__ rowp,
                                                const unsigned* __restrict__ ep,
                                                const __half* __restrict__ tin,
                                                const __half* __restrict__ prev,
                                                __half* __restrict__ tout,
                                                float alpha) {
    int idx = blockIdx.x * 256 + threadIdx.x;
    int n = idx >> 2, j8 = (idx & 3) << 3;
    int e0 = rowp[n], e1 = rowp[n + 1];
    const _Float16* tf = (const _Float16*)tin;
    float acc[8];
#pragma unroll
    for (int i = 0; i < 8; ++i) acc[i] = 0.f;
    int e = e0;
    int ea = (e0 + 3) & ~3;                 // align to 16B for vec4 meta loads
    if (ea > e1) ea = e1;
    for (; e < ea; ++e) {
        unsigned p = __builtin_nontemporal_load(ep + e);
        half8 v = *(const half8*)(tf + ((p & 0xFFFFu) << 5) + j8);
        float w = __half2float(__ushort_as_half((unsigned short)(p >> 16)));
#pragma unroll
        for (int i = 0; i < 8; ++i) acc[i] += w * (float)v[i];
    }
    int e8 = e + ((e1 - e) & ~7);
    for (; e < e8; e += 8) {                // 8 edges in flight
        uintx4 pa = __builtin_nontemporal_load((const uintx4*)(ep + e));
        uintx4 pb = __builtin_nontemporal_load((const uintx4*)(ep + e + 4));
        half8 v0 = *(const half8*)(tf + ((pa.x & 0xFFFFu) << 5) + j8);
        half8 v1 = *(const half8*)(tf + ((pa.y & 0xFFFFu) << 5) + j8);
        half8 v2 = *(const half8*)(tf + ((pa.z & 0xFFFFu) << 5) + j8);
        half8 v3 = *(const half8*)(tf + ((pa.w & 0xFFFFu) << 5) + j8);
        half8 v4 = *(const half8*)(tf + ((pb.x & 0xFFFFu) << 5) + j8);
        half8 v5 = *(const half8*)(tf + ((pb.y & 0xFFFFu) << 5) + j8);
        half8 v6 = *(const half8*)(tf + ((pb.z & 0xFFFFu) << 5) + j8);
        half8 v7 = *(const half8*)(tf + ((pb.w & 0xFFFFu) << 5) + j8);
        float w0 = __half2float(__ushort_as_half((unsigned short)(pa.x >> 16)));
        float w1 = __half2float(__ushort_as_half((unsigned short)(pa.y >> 16)));
        float w2 = __half2float(__ushort_as_half((unsigned short)(pa.z >> 16)));
        float w3 = __half2float(__ushort_as_half((unsigned short)(pa.w >> 16)));
        float w4 = __half2float(__ushort_as_half((unsigned short)(pb.x >> 16)));
        float w5 = __half2float(__ushort_as_half((unsigned short)(pb.y >> 16)));
        float w6 = __half2float(__ushort_as_half((unsigned short)(pb.z >> 16)));
        float w7 = __half2float(__ushort_as_half((unsigned short)(pb.w >> 16)));
#pragma unroll
        for (int i = 0; i < 8; ++i)
            acc[i] += w0 * (float)v0[i] + w1 * (float)v1[i]
                    + w2 * (float)v2[i] + w3 * (float)v3[i]
                    + w4 * (float)v4[i] + w5 * (float)v5[i]
                    + w6 * (float)v6[i] + w7 * (float)v7[i];
    }
    int e4 = e + ((e1 - e) & ~3);
    for (; e < e4; e += 4) {
        uintx4 pp = __builtin_nontemporal_load((const uintx4*)(ep + e));
        half8 v0 = *(const half8*)(tf + ((pp.x & 0xFFFFu) << 5) + j8);
        half8 v1 = *(const half8*)(tf + ((pp.y & 0xFFFFu) << 5) + j8);
        half8 v2 = *(const half8*)(tf + ((pp.z & 0xFFFFu) << 5) + j8);
        half8 v3 = *(const half8*)(tf + ((pp.w & 0xFFFFu) << 5) + j8);
        float w0 = __half2float(__ushort_as_half((unsigned short)(pp.x >> 16)));
        float w1 = __half2float(__ushort_as_half((unsigned short)(pp.y >> 16)));
        float w2 = __half2float(__ushort_as_half((unsigned short)(pp.z >> 16)));
        float w3 = __half2float(__ushort_as_half((unsigned short)(pp.w >> 16)));
#pragma unroll
        for (int i = 0; i < 8; ++i)
            acc[i] += w0 * (float)v0[i] + w1 * (float)v1[i]
                    + w2 * (float)v2[i] + w3 * (float)v3[i];
    }
    for (; e < e1; ++e) {
        unsigned p = __builtin_nontemporal_load(ep + e);
        half8 v = *(const half8*)(tf + ((p & 0xFFFFu) << 5) + j8);
        float w = __half2float(__ushort_as_half((unsigned short)(p >> 16)));
#pragma unroll
        for (int i = 0; i < 8; ++i) acc[i] += w * (float)v[i];
    }
    int o = (n << 5) + j8;
    half8 hr;
    if (prev) {
        half8 pv = *(const half8*)((const _Float16*)prev + o);
#pragma unroll
        for (int i = 0; i < 8; ++i) hr[i] = (_Float16)(alpha * acc[i] - (float)pv[i]);
    } else {
#pragma unroll
        for (int i = 0; i < 8; ++i) hr[i] = (_Float16)(alpha * acc[i]);
    }
    *(half8*)((_Float16*)tout + o) = hr;
}

// ---------------- layer-1 combine: h = relu(x*W[0] + sum_k tx_k*W[k] + b) ---
__global__ __launch_bounds__(256) void k_comb1(const float* __restrict__ x,
                                               const float* __restrict__ txr,
                                               const float* __restrict__ W,
                                               const float* __restrict__ b,
                                               __half* __restrict__ hout) {
    int idx = blockIdx.x * 256 + threadIdx.x;
    int n = idx >> 5, j = idx & 31;
    float acc = b[j] + x[n] * W[j];
#pragma unroll
    for (int k = 1; k < KCH; ++k)
        acc += txr[(k - 1) * NN + n] * W[k * HID + j];
    hout[idx] = __float2half(fmaxf(acc, 0.f));
}

// ------- fused converts: Wl->fp16 padded-40 (blocks 0..2047), W2/W3 -> fp16
//         transposed (2048..2087), out bias init (2088) --------------------
__global__ __launch_bounds__(256) void k_cvtall(const float* __restrict__ Wl,
                                                __half* __restrict__ Wlh,
                                                const float* __restrict__ W2,
                                                const float* __restrict__ W3,
                                                _Float16* __restrict__ Wt2,
                                                _Float16* __restrict__ Wt3,
                                                const float* __restrict__ bl,
                                                float* __restrict__ out) {
    int blk = blockIdx.x, tid = threadIdx.x;
    if (blk < 2048) {
        __shared__ float s[128 * 33];
        const float* src = Wl + (size_t)blk * 128 * 33;
        for (int t = tid; t < 128 * 33; t += 256) s[t] = src[t];
        __syncthreads();
        unsigned* dst = (unsigned*)(Wlh + (size_t)blk * 128 * WLP);
        for (int t = tid; t < 128 * (WLP / 2); t += 256) {
            int row = t / (WLP / 2), c2 = t - row * (WLP / 2);
            int c0 = 2 * c2;
            float f0 = (c0 < 33) ? s[row * 33 + c0] : 0.f;
            float f1 = (c0 + 1 < 33) ? s[row * 33 + c0 + 1] : 0.f;
            __half2 h = __floats2half2_rn(f0, f1);
            dst[t] = *(unsigned*)&h;
        }
    } else if (blk < 2088) {
        int t = (blk - 2048) * 256 + tid;     // 0..10239
        const float* W = (t < 5120) ? W2 : W3;
        _Float16* Wt   = (t < 5120) ? Wt2 : Wt3;
        int tt = (t < 5120) ? t : t - 5120;
        if (tt < KCH * HID * HID) {
            int kc = tt >> 10, rem = tt & 1023, j = rem >> 5, i = rem & 31;
            Wt[tt] = (_Float16)W[kc * 1024 + i * 32 + j];
        }
    } else {
        if (tid < NG * OUTS) out[tid] = bl[tid % OUTS];
    }
}

// ---------------- MFMA combine: h = act(sum_k tx_k @ W[k] + b) --------------
__global__ __launch_bounds__(256) void k_comb32(const __half* tx,
                                                const _Float16* __restrict__ Wt,
                                                const float* __restrict__ b,
                                                __half* hout,
                                                int relu) {
    int tid = threadIdx.x;
    int lane = tid & 63;
    int wave = (blockIdx.x * 256 + tid) >> 6;   // 0..1023
    int m = lane & 15, kg = lane >> 4;
    half8 Bf[KCH][2];
#pragma unroll
    for (int kc = 0; kc < KCH; ++kc)
#pragma unroll
        for (int h = 0; h < 2; ++h)
            Bf[kc][h] = *(const half8*)(Wt + kc * 1024 + (h * 16 + m) * 32 + kg * 8);
    float bj0 = b[m], bj1 = b[16 + m];
    const size_t S = (size_t)NN * HID;
    const _Float16* txf = (const _Float16*)tx;
#pragma unroll
    for (int t = 0; t < 4; ++t) {
        int nb = (wave * 4 + t) << 4;
        floatx4 acc0 = {0.f, 0.f, 0.f, 0.f}, acc1 = {0.f, 0.f, 0.f, 0.f};
#pragma unroll
        for (int kc = 0; kc < KCH; ++kc) {
            half8 Af = *(const half8*)(txf + (size_t)kc * S + (size_t)(nb + m) * 32 + kg * 8);
            acc0 = __builtin_amdgcn_mfma_f32_16x16x32_f16(Af, Bf[kc][0], acc0, 0, 0, 0);
            acc1 = __builtin_amdgcn_mfma_f32_16x16x32_f16(Af, Bf[kc][1], acc1, 0, 0, 0);
        }
        int rowb = nb + kg * 4;
#pragma unroll
        for (int r = 0; r < 4; ++r) {
            float v0 = acc0[r] + bj0, v1 = acc1[r] + bj1;
            if (relu) { v0 = fmaxf(v0, 0.f); v1 = fmaxf(v1, 0.f); }
            hout[(size_t)(rowb + r) * 32 + m]      = __float2half(v0);
            hout[(size_t)(rowb + r) * 32 + 16 + m] = __float2half(v1);
        }
    }
}

// ---------------- readout: 5x dwordx4 Wl rows ----------------
__global__ __launch_bounds__(256) void k_readout(const __half* __restrict__ h,
                                                 const __half* __restrict__ Wlh,
                                                 float* __restrict__ out) {
    int gp = blockIdx.x >> 7;
    int mc = blockIdx.x & 127;
    int tid = threadIdx.x;
    int g0 = gp * 2, g1 = g0 + 1;
    float acc0[OUTS], acc1[OUTS];
#pragma unroll
    for (int o = 0; o < OUTS; ++o) { acc0[o] = 0.f; acc1[o] = 0.f; }
    const __half* h0 = h + (size_t)g0 * GSZ;
    const __half* h1 = h + (size_t)g1 * GSZ;
    for (int it = 0; it < 8; ++it) {
        int m = mc * 2048 + it * 256 + tid;
        float hv0 = __half2float(h0[m]);
        float hv1 = __half2float(h1[m]);
        const uint4* rp = (const uint4*)(Wlh + (size_t)m * WLP);   // 80B rows, 16B aligned
        uint4 q0 = rp[0], q1 = rp[1], q2 = rp[2], q3 = rp[3], q4 = rp[4];
        unsigned u[17] = {q0.x, q0.y, q0.z, q0.w, q1.x, q1.y, q1.z, q1.w,
                          q2.x, q2.y, q2.z, q2.w, q3.x, q3.y, q3.z, q3.w, q4.x};
#pragma unroll
        for (int q = 0; q < 16; ++q) {
            float2 f = __half22float2(*(__half2*)&u[q]);
            acc0[2 * q]     += hv0 * f.x;  acc1[2 * q]     += hv1 * f.x;
            acc0[2 * q + 1] += hv0 * f.y;  acc1[2 * q + 1] += hv1 * f.y;
        }
        float lw = __half2float(__low2half(*(__half2*)&u[16]));
        acc0[32] += hv0 * lw;  acc1[32] += hv1 * lw;
    }
    __shared__ float red[4][2 * OUTS];
    int lane = tid & 63, w = tid >> 6;
#pragma unroll
    for (int o = 0; o < OUTS; ++o) {
        float v0 = acc0[o], v1 = acc1[o];
        for (int off = 32; off > 0; off >>= 1) {
            v0 += __shfl_down(v0, off, 64);
            v1 += __shfl_down(v1, off, 64);
        }
        if (lane == 0) { red[w][o] = v0; red[w][OUTS + o] = v1; }
    }
    __syncthreads();
    if (tid < 2 * OUTS) {
        float s = red[0][tid] + red[1][tid] + red[2][tid] + red[3][tid];
        int g = (tid < OUTS) ? g0 : g1;
        int o = (tid < OUTS) ? tid : tid - OUTS;
        atomicAdd(&out[g * OUTS + o], s);
    }
}

extern "C" void kernel_launch(void* const* d_in, const int* in_sizes, int n_in,
                              void* d_out, int out_size, void* d_ws, size_t ws_size,
                              hipStream_t stream) {
    const float* x  = (const float*)d_in[0];
    const int*   ei = (const int*)d_in[1];
    const float* W1 = (const float*)d_in[3];
    const float* b1 = (const float*)d_in[4];
    const float* W2 = (const float*)d_in[5];
    const float* b2 = (const float*)d_in[6];
    const float* W3 = (const float*)d_in[7];
    const float* b3 = (const float*)d_in[8];
    const float* Wl = (const float*)d_in[9];
    const float* bl = (const float*)d_in[10];
    float* out = (float*)d_out;

    char* ws = (char*)d_ws;
    size_t off = 0;
    auto alloc = [&](size_t bytes) -> void* {
        void* p = ws + off;
        off += (bytes + 255) & ~(size_t)255;
        return p;
    };
    unsigned char* pdeg = (unsigned char*)alloc((size_t)2 * SLICES * RSIZE);
    int*      bcnt   = (int*)alloc((size_t)128 * NBK * 4);
    int*      bbase  = (int*)alloc((size_t)257 * 4);
    int*      rowp   = (int*)alloc((size_t)(NN + 1) * 4);
    float*    dinv   = (float*)alloc((size_t)NN * 4);
    unsigned* bkt    = (unsigned*)alloc((size_t)EE * 4);
    unsigned* ep     = (unsigned*)alloc((size_t)EE * 4);
    float*    txw1   = (float*)alloc((size_t)4 * NN * 4);
    __half*   tx32   = (__half*)alloc((size_t)KCH * NN * HID * 2);
    __half*   hfin   = (__half*)alloc((size_t)NN * HID * 2);
    __half*   Wlh    = (__half*)alloc((size_t)GSZ * WLP * 2);
    _Float16* Wt2    = (_Float16*)alloc((size_t)KCH * HID * HID * 2);
    _Float16* Wt3    = (_Float16*)alloc((size_t)KCH * HID * HID * 2);

    // ---- CSR build (atomic-free) + weight converts + bias init ----
    k_hist2<<<256, 1024, 0, stream>>>(ei, pdeg, bcnt);
    k_hredscan<<<65, 256, 0, stream>>>(pdeg, dinv, bcnt, bbase);
    k_bucket<<<128, 1024, 0, stream>>>(ei, bcnt, bkt);
    k_place<<<256, 512, 0, stream>>>(bkt, bbase, dinv, ep, rowp);
    k_cvtall<<<2089, 256, 0, stream>>>(Wl, Wlh, W2, W3, Wt2, Wt3, bl, out);

    // ---- layer 1 (width-1, fp32 recurrence) ----
    float *t1 = txw1, *t2 = txw1 + NN, *t3 = txw1 + 2 * NN, *t4 = txw1 + 3 * NN;
    const int PG = (NN * 4) / 256;    // 1024 blocks, 4 lanes/node
    k_prop1<<<PG, 256, 0, stream>>>(rowp, ep, x,  nullptr, t1, 1.f);
    k_prop1<<<PG, 256, 0, stream>>>(rowp, ep, t1, x,       t2, 2.f);
    k_prop1<<<PG, 256, 0, stream>>>(rowp, ep, t2, t1,      t3, 2.f);
    k_prop1<<<PG, 256, 0, stream>>>(rowp, ep, t3, t2,      t4, 2.f);
    k_comb1<<<(NN * HID) / 256, 256, 0, stream>>>(x, txw1, W1, b1, tx32);

    const size_t S = (size_t)NN * HID;
    // ---- layer 2 ----
    k_prop32<<<PG, 256, 0, stream>>>(rowp, ep, tx32,         nullptr,      tx32 + 1 * S, 1.f);
    k_prop32<<<PG, 256, 0, stream>>>(rowp, ep, tx32 + 1 * S, tx32,         tx32 + 2 * S, 2.f);
    k_prop32<<<PG, 256, 0, stream>>>(rowp, ep, tx32 + 2 * S, tx32 + 1 * S, tx32 + 3 * S, 2.f);
    k_prop32<<<PG, 256, 0, stream>>>(rowp, ep, tx32 + 3 * S, tx32 + 2 * S, tx32 + 4 * S, 2.f);
    k_comb32<<<256, 256, 0, stream>>>(tx32, Wt2, b2, tx32, 1);   // in-place slot 0

    // ---- layer 3 (no relu) ----
    k_prop32<<<PG, 256, 0, stream>>>(rowp, ep, tx32,         nullptr,      tx32 + 1 * S, 1.f);
    k_prop32<<<PG, 256, 0, stream>>>(rowp, ep, tx32 + 1 * S, tx32,         tx32 + 2 * S, 2.f);
    k_prop32<<<PG, 256, 0, stream>>>(rowp, ep, tx32 + 2 * S, tx32 + 1 * S, tx32 + 3 * S, 2.f);
    k_prop32<<<PG, 256, 0, stream>>>(rowp, ep, tx32 + 3 * S, tx32 + 2 * S, tx32 + 4 * S, 2.f);
    k_comb32<<<256, 256, 0, stream>>>(tx32, Wt3, b3, hfin, 0);

    // ---- readout ----
    k_readout<<<512, 256, 0, stream>>>(hfin, Wlh, out);
}

// Round 14
// 417.173 us; speedup vs baseline: 1.1698x; 1.1698x over previous
//
#include <hip/hip_runtime.h>
#include <hip/hip_fp16.h>

#define NN     65536    // total nodes
#define EE     2097152  // edges
#define HID    32
#define KCH    5
#define OUTS   33
#define NG     8
#define GSZ    262144   // INPUT_SIZE * HIDDEN per graph
#define WLP    40       // padded fp16 row length for Wl (80 B, 16B-aligned)
#define SLICES 64       // edge slices for src histogram
#define RSIZE  32768    // counters per range (2 ranges cover 64K nodes)
#define BSL    16384    // edges per bucketing slice (128 slices)
#define NBK    256      // coarse buckets (dst >> 8)
#define STG    9472     // LDS staging capacity in k_place

typedef _Float16 half8 __attribute__((ext_vector_type(8)));
typedef float floatx4 __attribute__((ext_vector_type(4)));

// exclusive scan of sh[0..255] in place; whole block must call
__device__ __forceinline__ void exscan256(int tid, int* __restrict__ sh,
                                          int* __restrict__ wsc) {
    int v = 0, s = 0;
    if (tid < 256) {
        v = sh[tid];
        s = v;
        int lane = tid & 63;
        #pragma unroll
        for (int off = 1; off < 64; off <<= 1) {
            int t = __shfl_up(s, off, 64);
            if (lane >= off) s += t;
        }
        if (lane == 63) wsc[tid >> 6] = s;
    }
    __syncthreads();
    if (tid == 0) {
        int a = 0;
        #pragma unroll
        for (int i = 0; i < 4; ++i) { int t = wsc[i]; wsc[i] = a; a += t; }
    }
    __syncthreads();
    if (tid < 256) sh[tid] = s - v + wsc[tid >> 6];
    __syncthreads();
}

// ------- fused: src out-degree histogram (blocks 0..127) + dst bucket counts
__global__ __launch_bounds__(1024) void k_hist2(const int* __restrict__ ei,
                                                unsigned char* __restrict__ pdeg,
                                                int* __restrict__ bcnt) {
    __shared__ unsigned cnt[RSIZE];
    int b = blockIdx.x, tid = threadIdx.x;
    if (b < 128) {
        int r = (b >> 6) & 1, s = b & 63;
        const int* keys = ei + s * (EE / SLICES);
        unsigned char* pout = pdeg + (size_t)(r * SLICES + s) * RSIZE;
        for (int i = tid; i < RSIZE; i += 1024) cnt[i] = 0;
        __syncthreads();
        int lo = r * RSIZE, hi = lo + RSIZE;
        for (int i = tid; i < EE / SLICES; i += 1024) {
            int k = keys[i];
            if (k >= lo && k < hi) atomicAdd(&cnt[k - lo], 1u);
        }
        __syncthreads();
        unsigned* pout4 = (unsigned*)pout;
        for (int i = tid; i < RSIZE / 4; i += 1024) {
            unsigned c0 = cnt[4 * i], c1 = cnt[4 * i + 1];
            unsigned c2 = cnt[4 * i + 2], c3 = cnt[4 * i + 3];
            pout4[i] = c0 | (c1 << 8) | (c2 << 16) | (c3 << 24);
        }
    } else {
        int s = b - 128;
        if (tid < NBK) cnt[tid] = 0;
        __syncthreads();
        const int* dsts = ei + EE + s * BSL;
        for (int i = tid; i < BSL; i += 1024)
            atomicAdd(&cnt[dsts[i] >> 8], 1u);
        __syncthreads();
        if (tid < NBK) bcnt[s * NBK + tid] = (int)cnt[tid];
    }
}

// ------- fused: partial-hist reduce -> dinv (blocks 0..63) + bucket scan ----
__global__ __launch_bounds__(256) void k_hredscan(const unsigned char* __restrict__ pdeg,
                                                  float* __restrict__ dinv,
                                                  int* __restrict__ bcnt,
                                                  int* __restrict__ bbase) {
    int blk = blockIdx.x, tid = threadIdx.x;
    if (blk < 64) {
        int t = blk * 256 + tid;
        int r = t >> 13, ql = t & 8191;
        const unsigned* base = (const unsigned*)(pdeg + (size_t)r * SLICES * RSIZE) + ql;
        unsigned s0 = 0, s1 = 0, s2 = 0, s3 = 0;
#pragma unroll 8
        for (int s = 0; s < SLICES; ++s) {
            unsigned v = base[s * (RSIZE / 4)];
            s0 += v & 0xFF; s1 += (v >> 8) & 0xFF; s2 += (v >> 16) & 0xFF; s3 += v >> 24;
        }
        int c = (r << 15) + 4 * ql;
        dinv[c]     = s0 ? 1.0f / sqrtf((float)s0) : 0.0f;
        dinv[c + 1] = s1 ? 1.0f / sqrtf((float)s1) : 0.0f;
        dinv[c + 2] = s2 ? 1.0f / sqrtf((float)s2) : 0.0f;
        dinv[c + 3] = s3 ? 1.0f / sqrtf((float)s3) : 0.0f;
    } else {
        __shared__ int tot[256];
        __shared__ int wsc[4];
        int b = tid;
        int run = 0;
        for (int s = 0; s < 128; ++s) {
            int c = bcnt[s * NBK + b];
            bcnt[s * NBK + b] = run;
            run += c;
        }
        tot[b] = run;
        __syncthreads();
        exscan256(b, tot, wsc);
        bbase[b] = tot[b];
        if (b == 0) bbase[256] = EE;
        for (int s = 0; s < 128; ++s)
            bcnt[s * NBK + b] += tot[b];
    }
}

// ---------------- coarse bucketing: LDS counting sort, coalesced flush ------
__global__ __launch_bounds__(1024) void k_bucket(const int* __restrict__ ei,
                                                 const int* __restrict__ boff,
                                                 unsigned* __restrict__ bkt) {
    __shared__ unsigned stage[BSL];
    __shared__ int cnt[NBK], cur[NBK], gbase[NBK];
    __shared__ int wsc[4];
    int s = blockIdx.x, tid = threadIdx.x;
    if (tid < NBK) cnt[tid] = 0;
    __syncthreads();
    const int* srcs = ei + s * BSL;
    const int* dsts = ei + EE + s * BSL;
    for (int i = tid; i < BSL; i += 1024)
        atomicAdd(&cnt[dsts[i] >> 8], 1);
    __syncthreads();
    if (tid < NBK) gbase[tid] = boff[s * NBK + tid];
    exscan256(tid, cnt, wsc);
    if (tid < NBK) cur[tid] = cnt[tid];
    __syncthreads();
    for (int i = tid; i < BSL; i += 1024) {
        int d = dsts[i];
        int pos = atomicAdd(&cur[d >> 8], 1);
        stage[pos] = (unsigned)srcs[i] | ((unsigned)d << 16);
    }
    __syncthreads();
    for (int j = tid; j < BSL; j += 1024) {
        unsigned rec = stage[j];
        int b = rec >> 24;
        bkt[gbase[b] + (j - cnt[b])] = rec;
    }
}

// -------- fine placement: exact CSR, packed ep, rowp; per-dst edge lists
//          ordered low-src first then high-src (shrinks live gather set) ----
__global__ __launch_bounds__(512) void k_place(const unsigned* __restrict__ bkt,
                                               const int* __restrict__ bbase,
                                               const float* __restrict__ dinv,
                                               unsigned* __restrict__ ep,
                                               int* __restrict__ rowp) {
    __shared__ unsigned stage[STG];
    __shared__ int histL[NBK], histH[NBK], curL[NBK], curH[NBK];
    __shared__ float dl[NBK];
    __shared__ int wsc[4];
    int b = blockIdx.x, tid = threadIdx.x;
    int base = bbase[b], cnt = bbase[b + 1] - base;
    if (tid < NBK) { histL[tid] = 0; histH[tid] = 0; dl[tid] = dinv[b * NBK + tid]; }
    __syncthreads();
    const unsigned* recs = bkt + base;
    for (int i = tid; i < cnt; i += 512) {
        unsigned rec = recs[i];
        int dlow = (rec >> 16) & 255;
        if ((rec & 0xFFFFu) < 32768u) atomicAdd(&histL[dlow], 1);
        else                          atomicAdd(&histH[dlow], 1);
    }
    __syncthreads();
    if (tid < NBK) curL[tid] = histL[tid] + histH[tid];
    __syncthreads();
    exscan256(tid, curL, wsc);                  // curL = exclusive start per dlow
    if (tid < NBK) {
        int st = curL[tid];
        rowp[b * NBK + tid] = base + st;
        curH[tid] = st + histL[tid];            // high-src half starts after low
    }
    if (b == 0 && tid == 0) rowp[NN] = EE;
    __syncthreads();
    for (int i = tid; i < cnt; i += 512) {
        unsigned rec = recs[i];
        int srcv = rec & 0xFFFF;
        int dlow = (rec >> 16) & 255;
        float nr = -(dinv[srcv] * dl[dlow]);
        unsigned pk = (unsigned)srcv |
                      ((unsigned)__half_as_ushort(__float2half(nr)) << 16);
        int pos = (srcv < 32768) ? atomicAdd(&curL[dlow], 1)
                                 : atomicAdd(&curH[dlow], 1);
        if (pos < STG) stage[pos] = pk; else ep[base + pos] = pk;
    }
    __syncthreads();
    int lim = cnt < STG ? cnt : STG;
    for (int j = tid; j < lim; j += 512)
        ep[base + j] = stage[j];
}

// ------- width-1 propagation: 4 lanes/node, strided edges, shfl reduce ------
__global__ __launch_bounds__(256) void k_prop1(const int* __restrict__ rowp,
                                               const unsigned* __restrict__ ep,
                                               const float* __restrict__ tin,
                                               const float* __restrict__ prev,
                                               float* __restrict__ tout,
                                               float alpha) {
    int idx = blockIdx.x * 256 + threadIdx.x;
    int n = idx >> 2, l = idx & 3;
    int e0 = rowp[n], e1 = rowp[n + 1];
    float a = 0.f;
    for (int e = e0 + l; e < e1; e += 4) {
        unsigned p = ep[e];
        a += __half2float(__ushort_as_half((unsigned short)(p >> 16))) * tin[p & 0xFFFF];
    }
    a += __shfl_xor(a, 1, 64);
    a += __shfl_xor(a, 2, 64);
    if (l == 0) {
        float r = alpha * a;
        if (prev) r -= prev[n];
        tout[n] = r;
    }
}

// ---- width-32 fp16 propagation: 4 lanes/node, 16B gathers, 8-edge unroll ---
__global__ __launch_bounds__(256) void k_prop32(const int* __restrict__ rowp,
                                                const unsigned* __restrict__ ep,
                                                const __half* __restrict__ tin,
                                                const __half* __restrict__ prev,
                                                __half* __restrict__ tout,
                                                float alpha) {
    int idx = blockIdx.x * 256 + threadIdx.x;
    int n = idx >> 2, j8 = (idx & 3) << 3;
    int e0 = rowp[n], e1 = rowp[n + 1];
    const _Float16* tf = (const _Float16*)tin;
    float acc[8];
#pragma unroll
    for (int i = 0; i < 8; ++i) acc[i] = 0.f;
    int e = e0;
    int ea = (e0 + 3) & ~3;                 // align to 16B for uint4 meta loads
    if (ea > e1) ea = e1;
    for (; e < ea; ++e) {
        unsigned p = ep[e];
        half8 v = *(const half8*)(tf + ((p & 0xFFFFu) << 5) + j8);
        float w = __half2float(__ushort_as_half((unsigned short)(p >> 16)));
#pragma unroll
        for (int i = 0; i < 8; ++i) acc[i] += w * (float)v[i];
    }
    int e8 = e + ((e1 - e) & ~7);
    for (; e < e8; e += 8) {                // 8 edges in flight
        uint4 pa = *(const uint4*)(ep + e);
        uint4 pb = *(const uint4*)(ep + e + 4);
        half8 v0 = *(const half8*)(tf + ((pa.x & 0xFFFFu) << 5) + j8);
        half8 v1 = *(const half8*)(tf + ((pa.y & 0xFFFFu) << 5) + j8);
        half8 v2 = *(const half8*)(tf + ((pa.z & 0xFFFFu) << 5) + j8);
        half8 v3 = *(const half8*)(tf + ((pa.w & 0xFFFFu) << 5) + j8);
        half8 v4 = *(const half8*)(tf + ((pb.x & 0xFFFFu) << 5) + j8);
        half8 v5 = *(const half8*)(tf + ((pb.y & 0xFFFFu) << 5) + j8);
        half8 v6 = *(const half8*)(tf + ((pb.z & 0xFFFFu) << 5) + j8);
        half8 v7 = *(const half8*)(tf + ((pb.w & 0xFFFFu) << 5) + j8);
        float w0 = __half2float(__ushort_as_half((unsigned short)(pa.x >> 16)));
        float w1 = __half2float(__ushort_as_half((unsigned short)(pa.y >> 16)));
        float w2 = __half2float(__ushort_as_half((unsigned short)(pa.z >> 16)));
        float w3 = __half2float(__ushort_as_half((unsigned short)(pa.w >> 16)));
        float w4 = __half2float(__ushort_as_half((unsigned short)(pb.x >> 16)));
        float w5 = __half2float(__ushort_as_half((unsigned short)(pb.y >> 16)));
        float w6 = __half2float(__ushort_as_half((unsigned short)(pb.z >> 16)));
        float w7 = __half2float(__ushort_as_half((unsigned short)(pb.w >> 16)));
#pragma unroll
        for (int i = 0; i < 8; ++i)
            acc[i] += w0 * (float)v0[i] + w1 * (float)v1[i]
                    + w2 * (float)v2[i] + w3 * (float)v3[i]
                    + w4 * (float)v4[i] + w5 * (float)v5[i]
                    + w6 * (float)v6[i] + w7 * (float)v7[i];
    }
    int e4 = e + ((e1 - e) & ~3);
    for (; e < e4; e += 4) {
        uint4 pp = *(const uint4*)(ep + e);
        half8 v0 = *(const half8*)(tf + ((pp.x & 0xFFFFu) << 5) + j8);
        half8 v1 = *(const half8*)(tf + ((pp.y & 0xFFFFu) << 5) + j8);
        half8 v2 = *(const half8*)(tf + ((pp.z & 0xFFFFu) << 5) + j8);
        half8 v3 = *(const half8*)(tf + ((pp.w & 0xFFFFu) << 5) + j8);
        float w0 = __half2float(__ushort_as_half((unsigned short)(pp.x >> 16)));
        float w1 = __half2float(__ushort_as_half((unsigned short)(pp.y >> 16)));
        float w2 = __half2float(__ushort_as_half((unsigned short)(pp.z >> 16)));
        float w3 = __half2float(__ushort_as_half((unsigned short)(pp.w >> 16)));
#pragma unroll
        for (int i = 0; i < 8; ++i)
            acc[i] += w0 * (float)v0[i] + w1 * (float)v1[i]
                    + w2 * (float)v2[i] + w3 * (float)v3[i];
    }
    for (; e < e1; ++e) {
        unsigned p = ep[e];
        half8 v = *(const half8*)(tf + ((p & 0xFFFFu) << 5) + j8);
        float w = __half2float(__ushort_as_half((unsigned short)(p >> 16)));
#pragma unroll
        for (int i = 0; i < 8; ++i) acc[i] += w * (float)v[i];
    }
    int o = (n << 5) + j8;
    half8 hr;
    if (prev) {
        half8 pv = *(const half8*)((const _Float16*)prev + o);
#pragma unroll
        for (int i = 0; i < 8; ++i) hr[i] = (_Float16)(alpha * acc[i] - (float)pv[i]);
    } else {
#pragma unroll
        for (int i = 0; i < 8; ++i) hr[i] = (_Float16)(alpha * acc[i]);
    }
    *(half8*)((_Float16*)tout + o) = hr;
}

// ---------------- layer-1 combine: h = relu(x*W[0] + sum_k tx_k*W[k] + b) ---
__global__ __launch_bounds__(256) void k_comb1(const float* __restrict__ x,
                                               const float* __restrict__ txr,
                                               const float* __restrict__ W,
                                               const float* __restrict__ b,
                                               __half* __restrict__ hout) {
    int idx = blockIdx.x * 256 + threadIdx.x;
    int n = idx >> 5, j = idx & 31;
    float acc = b[j] + x[n] * W[j];
#pragma unroll
    for (int k = 1; k < KCH; ++k)
        acc += txr[(k - 1) * NN + n] * W[k * HID + j];
    hout[idx] = __float2half(fmaxf(acc, 0.f));
}

// ------- fused converts: Wl->fp16 padded-40 (blocks 0..2047), W2/W3 -> fp16
//         transposed (2048..2087), out bias init (2088) --------------------
__global__ __launch_bounds__(256) void k_cvtall(const float* __restrict__ Wl,
                                                __half* __restrict__ Wlh,
                                                const float* __restrict__ W2,
                                                const float* __restrict__ W3,
                                                _Float16* __restrict__ Wt2,
                                                _Float16* __restrict__ Wt3,
                                                const float* __restrict__ bl,
                                                float* __restrict__ out) {
    int blk = blockIdx.x, tid = threadIdx.x;
    if (blk < 2048) {
        __shared__ float s[128 * 33];
        const float* src = Wl + (size_t)blk * 128 * 33;
        for (int t = tid; t < 128 * 33; t += 256) s[t] = src[t];
        __syncthreads();
        unsigned* dst = (unsigned*)(Wlh + (size_t)blk * 128 * WLP);
        for (int t = tid; t < 128 * (WLP / 2); t += 256) {
            int row = t / (WLP / 2), c2 = t - row * (WLP / 2);
            int c0 = 2 * c2;
            float f0 = (c0 < 33) ? s[row * 33 + c0] : 0.f;
            float f1 = (c0 + 1 < 33) ? s[row * 33 + c0 + 1] : 0.f;
            __half2 h = __floats2half2_rn(f0, f1);
            dst[t] = *(unsigned*)&h;
        }
    } else if (blk < 2088) {
        int t = (blk - 2048) * 256 + tid;     // 0..10239
        const float* W = (t < 5120) ? W2 : W3;
        _Float16* Wt   = (t < 5120) ? Wt2 : Wt3;
        int tt = (t < 5120) ? t : t - 5120;
        if (tt < KCH * HID * HID) {
            int kc = tt >> 10, rem = tt & 1023, j = rem >> 5, i = rem & 31;
            Wt[tt] = (_Float16)W[kc * 1024 + i * 32 + j];
        }
    } else {
        if (tid < NG * OUTS) out[tid] = bl[tid % OUTS];
    }
}

// ---------------- MFMA combine: h = act(sum_k tx_k @ W[k] + b) --------------
__global__ __launch_bounds__(256) void k_comb32(const __half* tx,
                                                const _Float16* __restrict__ Wt,
                                                const float* __restrict__ b,
                                                __half* hout,
                                                int relu) {
    int tid = threadIdx.x;
    int lane = tid & 63;
    int wave = (blockIdx.x * 256 + tid) >> 6;   // 0..1023
    int m = lane & 15, kg = lane >> 4;
    half8 Bf[KCH][2];
#pragma unroll
    for (int kc = 0; kc < KCH; ++kc)
#pragma unroll
        for (int h = 0; h < 2; ++h)
            Bf[kc][h] = *(const half8*)(Wt + kc * 1024 + (h * 16 + m) * 32 + kg * 8);
    float bj0 = b[m], bj1 = b[16 + m];
    const size_t S = (size_t)NN * HID;
    const _Float16* txf = (const _Float16*)tx;
#pragma unroll
    for (int t = 0; t < 4; ++t) {
        int nb = (wave * 4 + t) << 4;
        floatx4 acc0 = {0.f, 0.f, 0.f, 0.f}, acc1 = {0.f, 0.f, 0.f, 0.f};
#pragma unroll
        for (int kc = 0; kc < KCH; ++kc) {
            half8 Af = *(const half8*)(txf + (size_t)kc * S + (size_t)(nb + m) * 32 + kg * 8);
            acc0 = __builtin_amdgcn_mfma_f32_16x16x32_f16(Af, Bf[kc][0], acc0, 0, 0, 0);
            acc1 = __builtin_amdgcn_mfma_f32_16x16x32_f16(Af, Bf[kc][1], acc1, 0, 0, 0);
        }
        int rowb = nb + kg * 4;
#pragma unroll
        for (int r = 0; r < 4; ++r) {
            float v0 = acc0[r] + bj0, v1 = acc1[r] + bj1;
            if (relu) { v0 = fmaxf(v0, 0.f); v1 = fmaxf(v1, 0.f); }
            hout[(size_t)(rowb + r) * 32 + m]      = __float2half(v0);
            hout[(size_t)(rowb + r) * 32 + 16 + m] = __float2half(v1);
        }
    }
}

// ---------------- readout: 5x dwordx4 Wl rows ----------------
__global__ __launch_bounds__(256) void k_readout(const __half* __restrict__ h,
                                                 const __half* __restrict__ Wlh,
                                                 float* __restrict__ out) {
    int gp = blockIdx.x >> 7;
    int mc = blockIdx.x & 127;
    int tid = threadIdx.x;
    int g0 = gp * 2, g1 = g0 + 1;
    float acc0[OUTS], acc1[OUTS];
#pragma unroll
    for (int o = 0; o < OUTS; ++o) { acc0[o] = 0.f; acc1[o] = 0.f; }
    const __half* h0 = h + (size_t)g0 * GSZ;
    const __half* h1 = h + (size_t)g1 * GSZ;
    for (int it = 0; it < 8; ++it) {
        int m = mc * 2048 + it * 256 + tid;
        float hv0 = __half2float(h0[m]);
        float hv1 = __half2float(h1[m]);
        const uint4* rp = (const uint4*)(Wlh + (size_t)m * WLP);   // 80B rows, 16B aligned
        uint4 q0 = rp[0], q1 = rp[1], q2 = rp[2], q3 = rp[3], q4 = rp[4];
        unsigned u[17] = {q0.x, q0.y, q0.z, q0.w, q1.x, q1.y, q1.z, q1.w,
                          q2.x, q2.y, q2.z, q2.w, q3.x, q3.y, q3.z, q3.w, q4.x};
#pragma unroll
        for (int q = 0; q < 16; ++q) {
            float2 f = __half22float2(*(__half2*)&u[q]);
            acc0[2 * q]     += hv0 * f.x;  acc1[2 * q]     += hv1 * f.x;
            acc0[2 * q + 1] += hv0 * f.y;  acc1[2 * q + 1] += hv1 * f.y;
        }
        float lw = __half2float(__low2half(*(__half2*)&u[16]));
        acc0[32] += hv0 * lw;  acc1[32] += hv1 * lw;
    }
    __shared__ float red[4][2 * OUTS];
    int lane = tid & 63, w = tid >> 6;
#pragma unroll
    for (int o = 0; o < OUTS; ++o) {
        float v0 = acc0[o], v1 = acc1[o];
        for (int off = 32; off > 0; off >>= 1) {
            v0 += __shfl_down(v0, off, 64);
            v1 += __shfl_down(v1, off, 64);
        }
        if (lane == 0) { red[w][o] = v0; red[w][OUTS + o] = v1; }
    }
    __syncthreads();
    if (tid < 2 * OUTS) {
        float s = red[0][tid] + red[1][tid] + red[2][tid] + red[3][tid];
        int g = (tid < OUTS) ? g0 : g1;
        int o = (tid < OUTS) ? tid : tid - OUTS;
        atomicAdd(&out[g * OUTS + o], s);
    }
}

extern "C" void kernel_launch(void* const* d_in, const int* in_sizes, int n_in,
                              void* d_out, int out_size, void* d_ws, size_t ws_size,
                              hipStream_t stream) {
    const float* x  = (const float*)d_in[0];
    const int*   ei = (const int*)d_in[1];
    const float* W1 = (const float*)d_in[3];
    const float* b1 = (const float*)d_in[4];
    const float* W2 = (const float*)d_in[5];
    const float* b2 = (const float*)d_in[6];
    const float* W3 = (const float*)d_in[7];
    const float* b3 = (const float*)d_in[8];
    const float* Wl = (const float*)d_in[9];
    const float* bl = (const float*)d_in[10];
    float* out = (float*)d_out;

    char* ws = (char*)d_ws;
    size_t off = 0;
    auto alloc = [&](size_t bytes) -> void* {
        void* p = ws + off;
        off += (bytes + 255) & ~(size_t)255;
        return p;
    };
    unsigned char* pdeg = (unsigned char*)alloc((size_t)2 * SLICES * RSIZE);
    int*      bcnt   = (int*)alloc((size_t)128 * NBK * 4);
    int*      bbase  = (int*)alloc((size_t)257 * 4);
    int*      rowp   = (int*)alloc((size_t)(NN + 1) * 4);
    float*    dinv   = (float*)alloc((size_t)NN * 4);
    unsigned* bkt    = (unsigned*)alloc((size_t)EE * 4);
    unsigned* ep     = (unsigned*)alloc((size_t)EE * 4);
    float*    txw1   = (float*)alloc((size_t)4 * NN * 4);
    __half*   tx32   = (__half*)alloc((size_t)KCH * NN * HID * 2);
    __half*   hfin   = (__half*)alloc((size_t)NN * HID * 2);
    __half*   Wlh    = (__half*)alloc((size_t)GSZ * WLP * 2);
    _Float16* Wt2    = (_Float16*)alloc((size_t)KCH * HID * HID * 2);
    _Float16* Wt3    = (_Float16*)alloc((size_t)KCH * HID * HID * 2);

    // ---- CSR build (atomic-free) + weight converts + bias init ----
    k_hist2<<<256, 1024, 0, stream>>>(ei, pdeg, bcnt);
    k_hredscan<<<65, 256, 0, stream>>>(pdeg, dinv, bcnt, bbase);
    k_bucket<<<128, 1024, 0, stream>>>(ei, bcnt, bkt);
    k_place<<<256, 512, 0, stream>>>(bkt, bbase, dinv, ep, rowp);
    k_cvtall<<<2089, 256, 0, stream>>>(Wl, Wlh, W2, W3, Wt2, Wt3, bl, out);

    // ---- layer 1 (width-1, fp32 recurrence) ----
    float *t1 = txw1, *t2 = txw1 + NN, *t3 = txw1 + 2 * NN, *t4 = txw1 + 3 * NN;
    const int PG = (NN * 4) / 256;    // 1024 blocks, 4 lanes/node
    k_prop1<<<PG, 256, 0, stream>>>(rowp, ep, x,  nullptr, t1, 1.f);
    k_prop1<<<PG, 256, 0, stream>>>(rowp, ep, t1, x,       t2, 2.f);
    k_prop1<<<PG, 256, 0, stream>>>(rowp, ep, t2, t1,      t3, 2.f);
    k_prop1<<<PG, 256, 0, stream>>>(rowp, ep, t3, t2,      t4, 2.f);
    k_comb1<<<(NN * HID) / 256, 256, 0, stream>>>(x, txw1, W1, b1, tx32);

    const size_t S = (size_t)NN * HID;
    // ---- layer 2 ----
    k_prop32<<<PG, 256, 0, stream>>>(rowp, ep, tx32,         nullptr,      tx32 + 1 * S, 1.f);
    k_prop32<<<PG, 256, 0, stream>>>(rowp, ep, tx32 + 1 * S, tx32,         tx32 + 2 * S, 2.f);
    k_prop32<<<PG, 256, 0, stream>>>(rowp, ep, tx32 + 2 * S, tx32 + 1 * S, tx32 + 3 * S, 2.f);
    k_prop32<<<PG, 256, 0, stream>>>(rowp, ep, tx32 + 3 * S, tx32 + 2 * S, tx32 + 4 * S, 2.f);
    k_comb32<<<256, 256, 0, stream>>>(tx32, Wt2, b2, tx32, 1);   // in-place slot 0

    // ---- layer 3 (no relu) ----
    k_prop32<<<PG, 256, 0, stream>>>(rowp, ep, tx32,         nullptr,      tx32 + 1 * S, 1.f);
    k_prop32<<<PG, 256, 0, stream>>>(rowp, ep, tx32 + 1 * S, tx32,         tx32 + 2 * S, 2.f);
    k_prop32<<<PG, 256, 0, stream>>>(rowp, ep, tx32 + 2 * S, tx32 + 1 * S, tx32 + 3 * S, 2.f);
    k_prop32<<<PG, 256, 0, stream>>>(rowp, ep, tx32 + 3 * S, tx32 + 2 * S, tx32 + 4 * S, 2.f);
    k_comb32<<<256, 256, 0, stream>>>(tx32, Wt3, b3, hfin, 0);

    // ---- readout ----
    k_readout<<<512, 256, 0, stream>>>(hfin, Wlh, out);
}

// Round 15
// 409.622 us; speedup vs baseline: 1.1914x; 1.0184x over previous
//
#include <hip/hip_runtime.h>
#include <hip/hip_fp16.h>

#define NN     65536    // total nodes
#define EE     2097152  // edges
#define HID    32
#define KCH    5
#define OUTS   33
#define NG     8
#define GSZ    262144   // INPUT_SIZE * HIDDEN per graph
#define WLP    40       // padded fp16 row length for Wl (80 B, 16B-aligned)
#define SLICES 64       // edge slices for src histogram
#define RSIZE  32768    // counters per range (2 ranges cover 64K nodes)
#define BSL    16384    // edges per bucketing slice (128 slices)
#define NBK    256      // coarse buckets (dst >> 8)
#define STG    9472     // LDS staging capacity in k_place
#define NPART  8        // src partitions per dst edge list (8192-node ranges)

typedef _Float16 half8 __attribute__((ext_vector_type(8)));
typedef float floatx4 __attribute__((ext_vector_type(4)));

// exclusive scan of sh[0..255] in place; whole block must call
__device__ __forceinline__ void exscan256(int tid, int* __restrict__ sh,
                                          int* __restrict__ wsc) {
    int v = 0, s = 0;
    if (tid < 256) {
        v = sh[tid];
        s = v;
        int lane = tid & 63;
        #pragma unroll
        for (int off = 1; off < 64; off <<= 1) {
            int t = __shfl_up(s, off, 64);
            if (lane >= off) s += t;
        }
        if (lane == 63) wsc[tid >> 6] = s;
    }
    __syncthreads();
    if (tid == 0) {
        int a = 0;
        #pragma unroll
        for (int i = 0; i < 4; ++i) { int t = wsc[i]; wsc[i] = a; a += t; }
    }
    __syncthreads();
    if (tid < 256) sh[tid] = s - v + wsc[tid >> 6];
    __syncthreads();
}

// ------- fused: src out-degree histogram (blocks 0..127) + dst bucket counts
__global__ __launch_bounds__(1024) void k_hist2(const int* __restrict__ ei,
                                                unsigned char* __restrict__ pdeg,
                                                int* __restrict__ bcnt) {
    __shared__ unsigned cnt[RSIZE];
    int b = blockIdx.x, tid = threadIdx.x;
    if (b < 128) {
        int r = (b >> 6) & 1, s = b & 63;
        const int* keys = ei + s * (EE / SLICES);
        unsigned char* pout = pdeg + (size_t)(r * SLICES + s) * RSIZE;
        for (int i = tid; i < RSIZE; i += 1024) cnt[i] = 0;
        __syncthreads();
        int lo = r * RSIZE, hi = lo + RSIZE;
        for (int i = tid; i < EE / SLICES; i += 1024) {
            int k = keys[i];
            if (k >= lo && k < hi) atomicAdd(&cnt[k - lo], 1u);
        }
        __syncthreads();
        unsigned* pout4 = (unsigned*)pout;
        for (int i = tid; i < RSIZE / 4; i += 1024) {
            unsigned c0 = cnt[4 * i], c1 = cnt[4 * i + 1];
            unsigned c2 = cnt[4 * i + 2], c3 = cnt[4 * i + 3];
            pout4[i] = c0 | (c1 << 8) | (c2 << 16) | (c3 << 24);
        }
    } else {
        int s = b - 128;
        if (tid < NBK) cnt[tid] = 0;
        __syncthreads();
        const int* dsts = ei + EE + s * BSL;
        for (int i = tid; i < BSL; i += 1024)
            atomicAdd(&cnt[dsts[i] >> 8], 1u);
        __syncthreads();
        if (tid < NBK) bcnt[s * NBK + tid] = (int)cnt[tid];
    }
}

// ------- fused: partial-hist reduce -> dinv (blocks 0..63) + bucket scan ----
__global__ __launch_bounds__(256) void k_hredscan(const unsigned char* __restrict__ pdeg,
                                                  float* __restrict__ dinv,
                                                  int* __restrict__ bcnt,
                                                  int* __restrict__ bbase) {
    int blk = blockIdx.x, tid = threadIdx.x;
    if (blk < 64) {
        int t = blk * 256 + tid;
        int r = t >> 13, ql = t & 8191;
        const unsigned* base = (const unsigned*)(pdeg + (size_t)r * SLICES * RSIZE) + ql;
        unsigned s0 = 0, s1 = 0, s2 = 0, s3 = 0;
#pragma unroll 8
        for (int s = 0; s < SLICES; ++s) {
            unsigned v = base[s * (RSIZE / 4)];
            s0 += v & 0xFF; s1 += (v >> 8) & 0xFF; s2 += (v >> 16) & 0xFF; s3 += v >> 24;
        }
        int c = (r << 15) + 4 * ql;
        dinv[c]     = s0 ? 1.0f / sqrtf((float)s0) : 0.0f;
        dinv[c + 1] = s1 ? 1.0f / sqrtf((float)s1) : 0.0f;
        dinv[c + 2] = s2 ? 1.0f / sqrtf((float)s2) : 0.0f;
        dinv[c + 3] = s3 ? 1.0f / sqrtf((float)s3) : 0.0f;
    } else {
        __shared__ int tot[256];
        __shared__ int wsc[4];
        int b = tid;
        int run = 0;
        for (int s = 0; s < 128; ++s) {
            int c = bcnt[s * NBK + b];
            bcnt[s * NBK + b] = run;
            run += c;
        }
        tot[b] = run;
        __syncthreads();
        exscan256(b, tot, wsc);
        bbase[b] = tot[b];
        if (b == 0) bbase[256] = EE;
        for (int s = 0; s < 128; ++s)
            bcnt[s * NBK + b] += tot[b];
    }
}

// ---------------- coarse bucketing: LDS counting sort, coalesced flush ------
__global__ __launch_bounds__(1024) void k_bucket(const int* __restrict__ ei,
                                                 const int* __restrict__ boff,
                                                 unsigned* __restrict__ bkt) {
    __shared__ unsigned stage[BSL];
    __shared__ int cnt[NBK], cur[NBK], gbase[NBK];
    __shared__ int wsc[4];
    int s = blockIdx.x, tid = threadIdx.x;
    if (tid < NBK) cnt[tid] = 0;
    __syncthreads();
    const int* srcs = ei + s * BSL;
    const int* dsts = ei + EE + s * BSL;
    for (int i = tid; i < BSL; i += 1024)
        atomicAdd(&cnt[dsts[i] >> 8], 1);
    __syncthreads();
    if (tid < NBK) gbase[tid] = boff[s * NBK + tid];
    exscan256(tid, cnt, wsc);
    if (tid < NBK) cur[tid] = cnt[tid];
    __syncthreads();
    for (int i = tid; i < BSL; i += 1024) {
        int d = dsts[i];
        int pos = atomicAdd(&cur[d >> 8], 1);
        stage[pos] = (unsigned)srcs[i] | ((unsigned)d << 16);
    }
    __syncthreads();
    for (int j = tid; j < BSL; j += 1024) {
        unsigned rec = stage[j];
        int b = rec >> 24;
        bkt[gbase[b] + (j - cnt[b])] = rec;
    }
}

// -------- fine placement: exact CSR, packed ep, rowp; per-dst edge lists
//          ordered in 8 src-range runs (shrinks live gather set to 512KB) ---
__global__ __launch_bounds__(512) void k_place(const unsigned* __restrict__ bkt,
                                               const int* __restrict__ bbase,
                                               const float* __restrict__ dinv,
                                               unsigned* __restrict__ ep,
                                               int* __restrict__ rowp) {
    __shared__ unsigned stage[STG];
    __shared__ int histP[NPART][NBK], curP[NPART][NBK];
    __shared__ int tot[NBK];
    __shared__ float dl[NBK];
    __shared__ int wsc[4];
    int b = blockIdx.x, tid = threadIdx.x;
    int base = bbase[b], cnt = bbase[b + 1] - base;
    if (tid < NBK) {
        dl[tid] = dinv[b * NBK + tid];
#pragma unroll
        for (int p = 0; p < NPART; ++p) histP[p][tid] = 0;
    }
    __syncthreads();
    const unsigned* recs = bkt + base;
    for (int i = tid; i < cnt; i += 512) {
        unsigned rec = recs[i];
        atomicAdd(&histP[(rec & 0xFFFFu) >> 13][(rec >> 16) & 255], 1);
    }
    __syncthreads();
    if (tid < NBK) {
        int s = 0;
#pragma unroll
        for (int p = 0; p < NPART; ++p) s += histP[p][tid];
        tot[tid] = s;
    }
    __syncthreads();
    exscan256(tid, tot, wsc);                   // tot = exclusive start per dlow
    if (tid < NBK) {
        int st = tot[tid];
        rowp[b * NBK + tid] = base + st;
#pragma unroll
        for (int p = 0; p < NPART; ++p) {
            curP[p][tid] = st;
            st += histP[p][tid];
        }
    }
    if (b == 0 && tid == 0) rowp[NN] = EE;
    __syncthreads();
    for (int i = tid; i < cnt; i += 512) {
        unsigned rec = recs[i];
        int srcv = rec & 0xFFFF;
        int dlow = (rec >> 16) & 255;
        float nr = -(dinv[srcv] * dl[dlow]);
        unsigned pk = (unsigned)srcv |
                      ((unsigned)__half_as_ushort(__float2half(nr)) << 16);
        int pos = atomicAdd(&curP[srcv >> 13][dlow], 1);
        if (pos < STG) stage[pos] = pk; else ep[base + pos] = pk;
    }
    __syncthreads();
    int lim = cnt < STG ? cnt : STG;
    for (int j = tid; j < lim; j += 512)
        ep[base + j] = stage[j];
}

// ------- width-1 propagation: 4 lanes/node, strided edges, shfl reduce ------
__global__ __launch_bounds__(256) void k_prop1(const int* __restrict__ rowp,
                                               const unsigned* __restrict__ ep,
                                               const float* __restrict__ tin,
                                               const float* __restrict__ prev,
                                               float* __restrict__ tout,
                                               float alpha) {
    int idx = blockIdx.x * 256 + threadIdx.x;
    int n = idx >> 2, l = idx & 3;
    int e0 = rowp[n], e1 = rowp[n + 1];
    float a = 0.f;
    for (int e = e0 + l; e < e1; e += 4) {
        unsigned p = ep[e];
        a += __half2float(__ushort_as_half((unsigned short)(p >> 16))) * tin[p & 0xFFFF];
    }
    a += __shfl_xor(a, 1, 64);
    a += __shfl_xor(a, 2, 64);
    if (l == 0) {
        float r = alpha * a;
        if (prev) r -= prev[n];
        tout[n] = r;
    }
}

// ---- width-32 fp16 propagation: 4 lanes/node, 16B gathers, 8-edge unroll ---
__global__ __launch_bounds__(256) void k_prop32(const int* __restrict__ rowp,
                                                const unsigned* __restrict__ ep,
                                                const __half* __restrict__ tin,
                                                const __half* __restrict__ prev,
                                                __half* __restrict__ tout,
                                                float alpha) {
    int idx = blockIdx.x * 256 + threadIdx.x;
    int n = idx >> 2, j8 = (idx & 3) << 3;
    int e0 = rowp[n], e1 = rowp[n + 1];
    const _Float16* tf = (const _Float16*)tin;
    float acc[8];
#pragma unroll
    for (int i = 0; i < 8; ++i) acc[i] = 0.f;
    int e = e0;
    int ea = (e0 + 3) & ~3;                 // align to 16B for uint4 meta loads
    if (ea > e1) ea = e1;
    for (; e < ea; ++e) {
        unsigned p = ep[e];
        half8 v = *(const half8*)(tf + ((p & 0xFFFFu) << 5) + j8);
        float w = __half2float(__ushort_as_half((unsigned short)(p >> 16)));
#pragma unroll
        for (int i = 0; i < 8; ++i) acc[i] += w * (float)v[i];
    }
    int e8 = e + ((e1 - e) & ~7);
    for (; e < e8; e += 8) {                // 8 edges in flight
        uint4 pa = *(const uint4*)(ep + e);
        uint4 pb = *(const uint4*)(ep + e + 4);
        half8 v0 = *(const half8*)(tf + ((pa.x & 0xFFFFu) << 5) + j8);
        half8 v1 = *(const half8*)(tf + ((pa.y & 0xFFFFu) << 5) + j8);
        half8 v2 = *(const half8*)(tf + ((pa.z & 0xFFFFu) << 5) + j8);
        half8 v3 = *(const half8*)(tf + ((pa.w & 0xFFFFu) << 5) + j8);
        half8 v4 = *(const half8*)(tf + ((pb.x & 0xFFFFu) << 5) + j8);
        half8 v5 = *(const half8*)(tf + ((pb.y & 0xFFFFu) << 5) + j8);
        half8 v6 = *(const half8*)(tf + ((pb.z & 0xFFFFu) << 5) + j8);
        half8 v7 = *(const half8*)(tf + ((pb.w & 0xFFFFu) << 5) + j8);
        float w0 = __half2float(__ushort_as_half((unsigned short)(pa.x >> 16)));
        float w1 = __half2float(__ushort_as_half((unsigned short)(pa.y >> 16)));
        float w2 = __half2float(__ushort_as_half((unsigned short)(pa.z >> 16)));
        float w3 = __half2float(__ushort_as_half((unsigned short)(pa.w >> 16)));
        float w4 = __half2float(__ushort_as_half((unsigned short)(pb.x >> 16)));
        float w5 = __half2float(__ushort_as_half((unsigned short)(pb.y >> 16)));
        float w6 = __half2float(__ushort_as_half((unsigned short)(pb.z >> 16)));
        float w7 = __half2float(__ushort_as_half((unsigned short)(pb.w >> 16)));
#pragma unroll
        for (int i = 0; i < 8; ++i)
            acc[i] += w0 * (float)v0[i] + w1 * (float)v1[i]
                    + w2 * (float)v2[i] + w3 * (float)v3[i]
                    + w4 * (float)v4[i] + w5 * (float)v5[i]
                    + w6 * (float)v6[i] + w7 * (float)v7[i];
    }
    int e4 = e + ((e1 - e) & ~3);
    for (; e < e4; e += 4) {
        uint4 pp = *(const uint4*)(ep + e);
        half8 v0 = *(const half8*)(tf + ((pp.x & 0xFFFFu) << 5) + j8);
        half8 v1 = *(const half8*)(tf + ((pp.y & 0xFFFFu) << 5) + j8);
        half8 v2 = *(const half8*)(tf + ((pp.z & 0xFFFFu) << 5) + j8);
        half8 v3 = *(const half8*)(tf + ((pp.w & 0xFFFFu) << 5) + j8);
        float w0 = __half2float(__ushort_as_half((unsigned short)(pp.x >> 16)));
        float w1 = __half2float(__ushort_as_half((unsigned short)(pp.y >> 16)));
        float w2 = __half2float(__ushort_as_half((unsigned short)(pp.z >> 16)));
        float w3 = __half2float(__ushort_as_half((unsigned short)(pp.w >> 16)));
#pragma unroll
        for (int i = 0; i < 8; ++i)
            acc[i] += w0 * (float)v0[i] + w1 * (float)v1[i]
                    + w2 * (float)v2[i] + w3 * (float)v3[i];
    }
    for (; e < e1; ++e) {
        unsigned p = ep[e];
        half8 v = *(const half8*)(tf + ((p & 0xFFFFu) << 5) + j8);
        float w = __half2float(__ushort_as_half((unsigned short)(p >> 16)));
#pragma unroll
        for (int i = 0; i < 8; ++i) acc[i] += w * (float)v[i];
    }
    int o = (n << 5) + j8;
    half8 hr;
    if (prev) {
        half8 pv = *(const half8*)((const _Float16*)prev + o);
#pragma unroll
        for (int i = 0; i < 8; ++i) hr[i] = (_Float16)(alpha * acc[i] - (float)pv[i]);
    } else {
#pragma unroll
        for (int i = 0; i < 8; ++i) hr[i] = (_Float16)(alpha * acc[i]);
    }
    *(half8*)((_Float16*)tout + o) = hr;
}

// ---------------- layer-1 combine: h = relu(x*W[0] + sum_k tx_k*W[k] + b) ---
__global__ __launch_bounds__(256) void k_comb1(const float* __restrict__ x,
                                               const float* __restrict__ txr,
                                               const float* __restrict__ W,
                                               const float* __restrict__ b,
                                               __half* __restrict__ hout) {
    int idx = blockIdx.x * 256 + threadIdx.x;
    int n = idx >> 5, j = idx & 31;
    float acc = b[j] + x[n] * W[j];
#pragma unroll
    for (int k = 1; k < KCH; ++k)
        acc += txr[(k - 1) * NN + n] * W[k * HID + j];
    hout[idx] = __float2half(fmaxf(acc, 0.f));
}

// ------- fused converts: Wl->fp16 padded-40 (blocks 0..2047), W2/W3 -> fp16
//         transposed (2048..2087), out bias init (2088) --------------------
__global__ __launch_bounds__(256) void k_cvtall(const float* __restrict__ Wl,
                                                __half* __restrict__ Wlh,
                                                const float* __restrict__ W2,
                                                const float* __restrict__ W3,
                                                _Float16* __restrict__ Wt2,
                                                _Float16* __restrict__ Wt3,
                                                const float* __restrict__ bl,
                                                float* __restrict__ out) {
    int blk = blockIdx.x, tid = threadIdx.x;
    if (blk < 2048) {
        __shared__ float s[128 * 33];
        const float* src = Wl + (size_t)blk * 128 * 33;
        for (int t = tid; t < 128 * 33; t += 256) s[t] = src[t];
        __syncthreads();
        unsigned* dst = (unsigned*)(Wlh + (size_t)blk * 128 * WLP);
        for (int t = tid; t < 128 * (WLP / 2); t += 256) {
            int row = t / (WLP / 2), c2 = t - row * (WLP / 2);
            int c0 = 2 * c2;
            float f0 = (c0 < 33) ? s[row * 33 + c0] : 0.f;
            float f1 = (c0 + 1 < 33) ? s[row * 33 + c0 + 1] : 0.f;
            __half2 h = __floats2half2_rn(f0, f1);
            dst[t] = *(unsigned*)&h;
        }
    } else if (blk < 2088) {
        int t = (blk - 2048) * 256 + tid;     // 0..10239
        const float* W = (t < 5120) ? W2 : W3;
        _Float16* Wt   = (t < 5120) ? Wt2 : Wt3;
        int tt = (t < 5120) ? t : t - 5120;
        if (tt < KCH * HID * HID) {
            int kc = tt >> 10, rem = tt & 1023, j = rem >> 5, i = rem & 31;
            Wt[tt] = (_Float16)W[kc * 1024 + i * 32 + j];
        }
    } else {
        if (tid < NG * OUTS) out[tid] = bl[tid % OUTS];
    }
}

// ---------------- MFMA combine: h = act(sum_k tx_k @ W[k] + b) --------------
__global__ __launch_bounds__(256) void k_comb32(const __half* tx,
                                                const _Float16* __restrict__ Wt,
                                                const float* __restrict__ b,
                                                __half* hout,
                                                int relu) {
    int tid = threadIdx.x;
    int lane = tid & 63;
    int wave = (blockIdx.x * 256 + tid) >> 6;   // 0..1023
    int m = lane & 15, kg = lane >> 4;
    half8 Bf[KCH][2];
#pragma unroll
    for (int kc = 0; kc < KCH; ++kc)
#pragma unroll
        for (int h = 0; h < 2; ++h)
            Bf[kc][h] = *(const half8*)(Wt + kc * 1024 + (h * 16 + m) * 32 + kg * 8);
    float bj0 = b[m], bj1 = b[16 + m];
    const size_t S = (size_t)NN * HID;
    const _Float16* txf = (const _Float16*)tx;
#pragma unroll
    for (int t = 0; t < 4; ++t) {
        int nb = (wave * 4 + t) << 4;
        floatx4 acc0 = {0.f, 0.f, 0.f, 0.f}, acc1 = {0.f, 0.f, 0.f, 0.f};
#pragma unroll
        for (int kc = 0; kc < KCH; ++kc) {
            half8 Af = *(const half8*)(txf + (size_t)kc * S + (size_t)(nb + m) * 32 + kg * 8);
            acc0 = __builtin_amdgcn_mfma_f32_16x16x32_f16(Af, Bf[kc][0], acc0, 0, 0, 0);
            acc1 = __builtin_amdgcn_mfma_f32_16x16x32_f16(Af, Bf[kc][1], acc1, 0, 0, 0);
        }
        int rowb = nb + kg * 4;
#pragma unroll
        for (int r = 0; r < 4; ++r) {
            float v0 = acc0[r] + bj0, v1 = acc1[r] + bj1;
            if (relu) { v0 = fmaxf(v0, 0.f); v1 = fmaxf(v1, 0.f); }
            hout[(size_t)(rowb + r) * 32 + m]      = __float2half(v0);
            hout[(size_t)(rowb + r) * 32 + 16 + m] = __float2half(v1);
        }
    }
}

// ---------------- readout: 5x dwordx4 Wl rows ----------------
__global__ __launch_bounds__(256) void k_readout(const __half* __restrict__ h,
                                                 const __half* __restrict__ Wlh,
                                                 float* __restrict__ out) {
    int gp = blockIdx.x >> 7;
    int mc = blockIdx.x & 127;
    int tid = threadIdx.x;
    int g0 = gp * 2, g1 = g0 + 1;
    float acc0[OUTS], acc1[OUTS];
#pragma unroll
    for (int o = 0; o < OUTS; ++o) { acc0[o] = 0.f; acc1[o] = 0.f; }
    const __half* h0 = h + (size_t)g0 * GSZ;
    const __half* h1 = h + (size_t)g1 * GSZ;
    for (int it = 0; it < 8; ++it) {
        int m = mc * 2048 + it * 256 + tid;
        float hv0 = __half2float(h0[m]);
        float hv1 = __half2float(h1[m]);
        const uint4* rp = (const uint4*)(Wlh + (size_t)m * WLP);   // 80B rows, 16B aligned
        uint4 q0 = rp[0], q1 = rp[1], q2 = rp[2], q3 = rp[3], q4 = rp[4];
        unsigned u[17] = {q0.x, q0.y, q0.z, q0.w, q1.x, q1.y, q1.z, q1.w,
                          q2.x, q2.y, q2.z, q2.w, q3.x, q3.y, q3.z, q3.w, q4.x};
#pragma unroll
        for (int q = 0; q < 16; ++q) {
            float2 f = __half22float2(*(__half2*)&u[q]);
            acc0[2 * q]     += hv0 * f.x;  acc1[2 * q]     += hv1 * f.x;
            acc0[2 * q + 1] += hv0 * f.y;  acc1[2 * q + 1] += hv1 * f.y;
        }
        float lw = __half2float(__low2half(*(__half2*)&u[16]));
        acc0[32] += hv0 * lw;  acc1[32] += hv1 * lw;
    }
    __shared__ float red[4][2 * OUTS];
    int lane = tid & 63, w = tid >> 6;
#pragma unroll
    for (int o = 0; o < OUTS; ++o) {
        float v0 = acc0[o], v1 = acc1[o];
        for (int off = 32; off > 0; off >>= 1) {
            v0 += __shfl_down(v0, off, 64);
            v1 += __shfl_down(v1, off, 64);
        }
        if (lane == 0) { red[w][o] = v0; red[w][OUTS + o] = v1; }
    }
    __syncthreads();
    if (tid < 2 * OUTS) {
        float s = red[0][tid] + red[1][tid] + red[2][tid] + red[3][tid];
        int g = (tid < OUTS) ? g0 : g1;
        int o = (tid < OUTS) ? tid : tid - OUTS;
        atomicAdd(&out[g * OUTS + o], s);
    }
}

extern "C" void kernel_launch(void* const* d_in, const int* in_sizes, int n_in,
                              void* d_out, int out_size, void* d_ws, size_t ws_size,
                              hipStream_t stream) {
    const float* x  = (const float*)d_in[0];
    const int*   ei = (const int*)d_in[1];
    const float* W1 = (const float*)d_in[3];
    const float* b1 = (const float*)d_in[4];
    const float* W2 = (const float*)d_in[5];
    const float* b2 = (const float*)d_in[6];
    const float* W3 = (const float*)d_in[7];
    const float* b3 = (const float*)d_in[8];
    const float* Wl = (const float*)d_in[9];
    const float* bl = (const float*)d_in[10];
    float* out = (float*)d_out;

    char* ws = (char*)d_ws;
    size_t off = 0;
    auto alloc = [&](size_t bytes) -> void* {
        void* p = ws + off;
        off += (bytes + 255) & ~(size_t)255;
        return p;
    };
    unsigned char* pdeg = (unsigned char*)alloc((size_t)2 * SLICES * RSIZE);
    int*      bcnt   = (int*)alloc((size_t)128 * NBK * 4);
    int*      bbase  = (int*)alloc((size_t)257 * 4);
    int*      rowp   = (int*)alloc((size_t)(NN + 1) * 4);
    float*    dinv   = (float*)alloc((size_t)NN * 4);
    unsigned* bkt    = (unsigned*)alloc((size_t)EE * 4);
    unsigned* ep     = (unsigned*)alloc((size_t)EE * 4);
    float*    txw1   = (float*)alloc((size_t)4 * NN * 4);
    __half*   tx32   = (__half*)alloc((size_t)KCH * NN * HID * 2);
    __half*   hfin   = (__half*)alloc((size_t)NN * HID * 2);
    __half*   Wlh    = (__half*)alloc((size_t)GSZ * WLP * 2);
    _Float16* Wt2    = (_Float16*)alloc((size_t)KCH * HID * HID * 2);
    _Float16* Wt3    = (_Float16*)alloc((size_t)KCH * HID * HID * 2);

    // ---- CSR build (atomic-free) + weight converts + bias init ----
    k_hist2<<<256, 1024, 0, stream>>>(ei, pdeg, bcnt);
    k_hredscan<<<65, 256, 0, stream>>>(pdeg, dinv, bcnt, bbase);
    k_bucket<<<128, 1024, 0, stream>>>(ei, bcnt, bkt);
    k_place<<<256, 512, 0, stream>>>(bkt, bbase, dinv, ep, rowp);
    k_cvtall<<<2089, 256, 0, stream>>>(Wl, Wlh, W2, W3, Wt2, Wt3, bl, out);

    // ---- layer 1 (width-1, fp32 recurrence) ----
    float *t1 = txw1, *t2 = txw1 + NN, *t3 = txw1 + 2 * NN, *t4 = txw1 + 3 * NN;
    const int PG = (NN * 4) / 256;    // 1024 blocks, 4 lanes/node
    k_prop1<<<PG, 256, 0, stream>>>(rowp, ep, x,  nullptr, t1, 1.f);
    k_prop1<<<PG, 256, 0, stream>>>(rowp, ep, t1, x,       t2, 2.f);
    k_prop1<<<PG, 256, 0, stream>>>(rowp, ep, t2, t1,      t3, 2.f);
    k_prop1<<<PG, 256, 0, stream>>>(rowp, ep, t3, t2,      t4, 2.f);
    k_comb1<<<(NN * HID) / 256, 256, 0, stream>>>(x, txw1, W1, b1, tx32);

    const size_t S = (size_t)NN * HID;
    // ---- layer 2 ----
    k_prop32<<<PG, 256, 0, stream>>>(rowp, ep, tx32,         nullptr,      tx32 + 1 * S, 1.f);
    k_prop32<<<PG, 256, 0, stream>>>(rowp, ep, tx32 + 1 * S, tx32,         tx32 + 2 * S, 2.f);
    k_prop32<<<PG, 256, 0, stream>>>(rowp, ep, tx32 + 2 * S, tx32 + 1 * S, tx32 + 3 * S, 2.f);
    k_prop32<<<PG, 256, 0, stream>>>(rowp, ep, tx32 + 3 * S, tx32 + 2 * S, tx32 + 4 * S, 2.f);
    k_comb32<<<256, 256, 0, stream>>>(tx32, Wt2, b2, tx32, 1);   // in-place slot 0

    // ---- layer 3 (no relu) ----
    k_prop32<<<PG, 256, 0, stream>>>(rowp, ep, tx32,         nullptr,      tx32 + 1 * S, 1.f);
    k_prop32<<<PG, 256, 0, stream>>>(rowp, ep, tx32 + 1 * S, tx32,         tx32 + 2 * S, 2.f);
    k_prop32<<<PG, 256, 0, stream>>>(rowp, ep, tx32 + 2 * S, tx32 + 1 * S, tx32 + 3 * S, 2.f);
    k_prop32<<<PG, 256, 0, stream>>>(rowp, ep, tx32 + 3 * S, tx32 + 2 * S, tx32 + 4 * S, 2.f);
    k_comb32<<<256, 256, 0, stream>>>(tx32, Wt3, b3, hfin, 0);

    // ---- readout ----
    k_readout<<<512, 256, 0, stream>>>(hfin, Wlh, out);
}